// Round 9
// baseline (8717.288 us; speedup 1.0000x reference)
//
#include <hip/hip_runtime.h>
#include <hip/hip_bf16.h>

#define B_ 64
#define T_ 512
#define D_ 1024
#define H_ 1024
#define NB64 64   // fallback persistent blocks (round-8 validated)
#define NB16 16   // primary persistent blocks (64 cols each)

typedef __bf16 bf16x8 __attribute__((ext_vector_type(8)));
typedef float f32x4 __attribute__((ext_vector_type(4)));

static __device__ __forceinline__ unsigned short f2bf(float f) {
  union { float f; unsigned u; } v; v.f = f;
  unsigned u = v.u;
  unsigned r = (u + 0x7fffu + ((u >> 16) & 1u)) >> 16;
  return (unsigned short)r;
}

// ---------------------------------------------------------------------------
// xi = x @ Wi^T + bi -> out[B,T,H]  (validated rounds 2/5/6/7/8)
// ---------------------------------------------------------------------------
__global__ __launch_bounds__(256) void xi_gemm(const float* __restrict__ x,
                                               const float* __restrict__ Wi,
                                               const float* __restrict__ bi,
                                               float* __restrict__ out) {
  __shared__ __align__(16) unsigned short As[128][40];
  __shared__ __align__(16) unsigned short Ws[128][40];
  const int tid = threadIdx.x;
  const int wave = tid >> 6;
  const int lane = tid & 63;
  const int wm = wave >> 1, wn = wave & 1;
  const int lr = lane & 15, lk = lane >> 4;
  const long row0 = (long)blockIdx.x * 128;
  const int col0 = (int)blockIdx.y * 128;

  f32x4 acc[4][4];
#pragma unroll
  for (int m = 0; m < 4; ++m)
#pragma unroll
    for (int n = 0; n < 4; ++n)
      acc[m][n] = (f32x4){0.f, 0.f, 0.f, 0.f};

  for (int kt = 0; kt < 32; ++kt) {
    __syncthreads();
#pragma unroll
    for (int it = 0; it < 4; ++it) {
      int i = tid + it * 256;
      int row = i >> 3, c = i & 7;
      float4 va = *reinterpret_cast<const float4*>(
          &x[(row0 + row) * 1024 + kt * 32 + c * 4]);
      ushort4 ba = {f2bf(va.x), f2bf(va.y), f2bf(va.z), f2bf(va.w)};
      *reinterpret_cast<ushort4*>(&As[row][c * 4]) = ba;
      float4 vw = *reinterpret_cast<const float4*>(
          &Wi[(long)(col0 + row) * 1024 + kt * 32 + c * 4]);
      ushort4 bw = {f2bf(vw.x), f2bf(vw.y), f2bf(vw.z), f2bf(vw.w)};
      *reinterpret_cast<ushort4*>(&Ws[row][c * 4]) = bw;
    }
    __syncthreads();
    bf16x8 af[4], wf[4];
#pragma unroll
    for (int m = 0; m < 4; ++m)
      af[m] = *reinterpret_cast<const bf16x8*>(&As[wm * 64 + m * 16 + lr][lk * 8]);
#pragma unroll
    for (int n = 0; n < 4; ++n)
      wf[n] = *reinterpret_cast<const bf16x8*>(&Ws[wn * 64 + n * 16 + lr][lk * 8]);
#pragma unroll
    for (int m = 0; m < 4; ++m)
#pragma unroll
      for (int n = 0; n < 4; ++n)
        acc[m][n] = __builtin_amdgcn_mfma_f32_16x16x32_bf16(af[m], wf[n], acc[m][n], 0, 0, 0);
  }
#pragma unroll
  for (int m = 0; m < 4; ++m) {
#pragma unroll
    for (int n = 0; n < 4; ++n) {
#pragma unroll
      for (int r = 0; r < 4; ++r) {
        long row = row0 + wm * 64 + m * 16 + lk * 4 + r;
        int col = col0 + wn * 64 + n * 16 + lr;
        out[row * 1024 + col] = acc[m][n][r] + bi[col];
      }
    }
  }
}

// ---------------------------------------------------------------------------
// Primary: 16 fat blocks x 1024 thr (16 waves), 64 cols each.
// Wh slice = [64][1032] ushort, 132 KB DYNAMIC LDS. Same barrier protocol as
// round 8 (flag array, sc1 h publication, acquire-inv) but:
//  - only 16 flag slots x 16 polling lanes -> 16x less LLC flag contention
//  - s_sleep(2) backoff -> poll rounds ~2x sparser
//  - xi prefetched into regs BEFORE the barrier (latency hidden under wait)
// Wave w: wq=w>>2 batch quad (rows wq*16..+15), wn=w&3 col quad.
// ws: flags 64x64B (4 KB) | h hi[2][64][1024] ushort (256 KB).
// ---------------------------------------------------------------------------
__global__ __launch_bounds__(1024) void rnn_persist16(const float* __restrict__ Wh,
                                                      const float* __restrict__ bh,
                                                      float* __restrict__ out,
                                                      unsigned* __restrict__ flags,
                                                      unsigned short* __restrict__ hs) {
  extern __shared__ __align__(16) unsigned short Whs[];  // [64][1032]
  const int tid = threadIdx.x;
  const int wave = tid >> 6, lane = tid & 63;
  const int lr = lane & 15, lk = lane >> 4;
  const int wq = wave >> 2, wn = wave & 3;
  const int j0 = blockIdx.x * 64;

  // stage Wh rows j0..j0+63 -> LDS bf16 (once): 64 x 256 float4-chunks
#pragma unroll
  for (int it = 0; it < 16; ++it) {
    int i = tid + it * 1024;
    int row = i >> 8, c = i & 255;
    float4 v = *reinterpret_cast<const float4*>(&Wh[(long)(j0 + row) * 1024 + c * 4]);
    ushort4 b4 = {f2bf(v.x), f2bf(v.y), f2bf(v.z), f2bf(v.w)};
    *reinterpret_cast<ushort4*>(&Whs[row * 1032 + c * 4]) = b4;
  }
  const int jcol = j0 + wn * 16 + lr;
  const float bhv = bh[jcol];
  __syncthreads();

  const int brow = wq * 16;                                  // batch-row tile
  const unsigned short* wbl = &Whs[(wn * 16 + lr) * 1032 + lk * 8];  // B-frag
  unsigned* hw = reinterpret_cast<unsigned*>(hs);

  for (int t = 0; t < T_; ++t) {
    // xi prefetch for THIS step (independent of h) — hides under barrier wait
    float xr[4];
#pragma unroll
    for (int r = 0; r < 4; ++r) {
      int b = brow + lk * 4 + r;
      xr[r] = out[((size_t)b * T_ + t) * H_ + jcol];
    }

    if (t > 0) {
      __syncthreads();  // all waves' sc1 h-stores drained (at LLC)
      if (tid < 64) {   // wave 0 runs the barrier
        if (tid == 0)
          __hip_atomic_store(&flags[(unsigned)blockIdx.x << 4], (unsigned)t,
                             __ATOMIC_RELAXED, __HIP_MEMORY_SCOPE_AGENT);
        unsigned spin = 0;
        for (;;) {
          unsigned v = (unsigned)t;
          if (tid < NB16)
            v = __hip_atomic_load(&flags[(unsigned)tid << 4],
                                  __ATOMIC_RELAXED, __HIP_MEMORY_SCOPE_AGENT);
          if (__all((int)(v >= (unsigned)t))) break;
          __builtin_amdgcn_s_sleep(2);
          if (++spin > 100000u) break;  // fail loud, never wedge
        }
        __builtin_amdgcn_fence(__ATOMIC_ACQUIRE, "agent");  // buffer_inv
      }
      __syncthreads();  // other waves wait for inv before reading h
    }

    f32x4 a0 = {0, 0, 0, 0}, a1 = {0, 0, 0, 0};
    if (t > 0) {
      const size_t pb = (size_t)((t - 1) & 1) * 65536;   // parity base (ushort)
      const unsigned short* hbl = hs + pb + (size_t)(brow + lr) * 1024 + lk * 8;
      // 2 independent MFMA chains (two K-halves), 16 deep each; cached loads
#pragma unroll 4
      for (int ks = 0; ks < 16; ++ks) {
        bf16x8 ah0 = *reinterpret_cast<const bf16x8*>(hbl + ks * 32);
        bf16x8 ah1 = *reinterpret_cast<const bf16x8*>(hbl + (ks + 16) * 32);
        bf16x8 wf0 = *reinterpret_cast<const bf16x8*>(wbl + ks * 32);
        bf16x8 wf1 = *reinterpret_cast<const bf16x8*>(wbl + (ks + 16) * 32);
        a0 = __builtin_amdgcn_mfma_f32_16x16x32_bf16(ah0, wf0, a0, 0, 0, 0);
        a1 = __builtin_amdgcn_mfma_f32_16x16x32_bf16(ah1, wf1, a1, 0, 0, 0);
      }
    }
    f32x4 acc = a0 + a1;

    // epilogue (m89 D-layout): lane owns col jcol, rows brow + lk*4 + r
    const unsigned pw = (unsigned)(t & 1) * 32768u;      // parity base (u32)
#pragma unroll
    for (int r = 0; r < 4; ++r) {
      int b = brow + lk * 4 + r;
      size_t oi = ((size_t)b * T_ + t) * H_ + jcol;
      float z = xr[r] + acc[r] + bhv;
      float h = tanhf(z);
      out[oi] = h;
      unsigned hi_u = f2bf(h);
      unsigned o_hi = (unsigned)__shfl_xor((int)hi_u, 1, 64);
      if ((lr & 1) == 0) {
        __hip_atomic_store(&hw[pw + (unsigned)b * 512u + ((unsigned)jcol >> 1)],
                           hi_u | (o_hi << 16),
                           __ATOMIC_RELAXED, __HIP_MEMORY_SCOPE_AGENT);
      }
    }
  }
}

// ---------------------------------------------------------------------------
// Fallback: round-8 validated 64-block persistent kernel (static 33 KB LDS).
// ---------------------------------------------------------------------------
__global__ __launch_bounds__(256) void rnn_persist64(const float* __restrict__ Wh,
                                                     const float* __restrict__ bh,
                                                     float* __restrict__ out,
                                                     unsigned* __restrict__ flags,
                                                     unsigned short* __restrict__ hs) {
  __shared__ __align__(16) unsigned short Whs[16][1032];
  const int tid = threadIdx.x;
  const int wave = tid >> 6, lane = tid & 63;
  const int lr = lane & 15, lk = lane >> 4;
  const int j0 = blockIdx.x * 16;

#pragma unroll
  for (int it = 0; it < 16; ++it) {
    int i = tid + it * 256;
    int row = i >> 8, c = i & 255;
    float4 v = *reinterpret_cast<const float4*>(&Wh[(long)(j0 + row) * 1024 + c * 4]);
    ushort4 b4 = {f2bf(v.x), f2bf(v.y), f2bf(v.z), f2bf(v.w)};
    *reinterpret_cast<ushort4*>(&Whs[row][c * 4]) = b4;
  }
  const float bhv = bh[j0 + lr];
  __syncthreads();

  const int brow = wave * 16;
  const unsigned short* wbl = &Whs[lr][lk * 8];
  unsigned* hw = reinterpret_cast<unsigned*>(hs);
  const int jp = (j0 >> 1) + (lr >> 1);

  for (int t = 0; t < T_; ++t) {
    if (t > 0) {
      __syncthreads();
      if (tid < 64) {
        if (tid == 0)
          __hip_atomic_store(&flags[(unsigned)blockIdx.x << 4], (unsigned)t,
                             __ATOMIC_RELAXED, __HIP_MEMORY_SCOPE_AGENT);
        unsigned spin = 0;
        for (;;) {
          unsigned v = __hip_atomic_load(&flags[(unsigned)tid << 4],
                                         __ATOMIC_RELAXED, __HIP_MEMORY_SCOPE_AGENT);
          if (__all((int)(v >= (unsigned)t))) break;
          __builtin_amdgcn_s_sleep(1);
          if (++spin > 50000u) break;
        }
        __builtin_amdgcn_fence(__ATOMIC_ACQUIRE, "agent");
      }
      __syncthreads();
    }

    f32x4 a0 = {0, 0, 0, 0}, a1 = {0, 0, 0, 0};
    if (t > 0) {
      const size_t pb = (size_t)((t - 1) & 1) * 65536;
      const unsigned short* hbl = hs + pb + (size_t)(brow + lr) * 1024 + lk * 8;
#pragma unroll 4
      for (int ks = 0; ks < 16; ++ks) {
        bf16x8 ah0 = *reinterpret_cast<const bf16x8*>(hbl + ks * 32);
        bf16x8 ah1 = *reinterpret_cast<const bf16x8*>(hbl + (ks + 16) * 32);
        bf16x8 wf0 = *reinterpret_cast<const bf16x8*>(wbl + ks * 32);
        bf16x8 wf1 = *reinterpret_cast<const bf16x8*>(wbl + (ks + 16) * 32);
        a0 = __builtin_amdgcn_mfma_f32_16x16x32_bf16(ah0, wf0, a0, 0, 0, 0);
        a1 = __builtin_amdgcn_mfma_f32_16x16x32_bf16(ah1, wf1, a1, 0, 0, 0);
      }
    }
    f32x4 acc = a0 + a1;

    const unsigned pw = (unsigned)(t & 1) * 32768u;
    const int jcol = j0 + lr;
#pragma unroll
    for (int r = 0; r < 4; ++r) {
      int b = brow + lk * 4 + r;
      size_t oi = ((size_t)b * T_ + t) * H_ + jcol;
      float z = out[oi] + acc[r] + bhv;
      float h = tanhf(z);
      out[oi] = h;
      unsigned hi_u = f2bf(h);
      unsigned o_hi = (unsigned)__shfl_xor((int)hi_u, 1, 64);
      if ((lr & 1) == 0) {
        __hip_atomic_store(&hw[pw + (unsigned)b * 512u + (unsigned)jp],
                           hi_u | (o_hi << 16),
                           __ATOMIC_RELAXED, __HIP_MEMORY_SCOPE_AGENT);
      }
    }
  }
}

// ---------------------------------------------------------------------------
// Last-resort fallback (round-2 validated): per-step kernel chain.
// ---------------------------------------------------------------------------
__global__ __launch_bounds__(256) void rnn_step(const float* __restrict__ Wh,
                                                const float* __restrict__ bh,
                                                float* __restrict__ out,
                                                int t) {
  const int bg = blockIdx.x & 3;
  const int jg = blockIdx.x >> 2;
  const int b = bg * 16 + (threadIdx.x >> 4);
  const int j = jg * 16 + (threadIdx.x & 15);
  float a0 = 0.f, a1 = 0.f, a2 = 0.f, a3 = 0.f;
  if (t > 0) {
    const float4* __restrict__ wr = reinterpret_cast<const float4*>(&Wh[(long)j * H_]);
    const float4* __restrict__ hr = reinterpret_cast<const float4*>(
        &out[((long)b * T_ + (t - 1)) * H_]);
#pragma unroll 8
    for (int kc = 0; kc < 256; ++kc) {
      float4 w = wr[kc];
      float4 h = hr[kc];
      a0 = fmaf(w.x, h.x, a0);
      a1 = fmaf(w.y, h.y, a1);
      a2 = fmaf(w.z, h.z, a2);
      a3 = fmaf(w.w, h.w, a3);
    }
  }
  const long oi = ((long)b * T_ + t) * H_ + j;
  float z = out[oi] + ((a0 + a1) + (a2 + a3)) + bh[j];
  out[oi] = tanhf(z);
}

extern "C" void kernel_launch(void* const* d_in, const int* in_sizes, int n_in,
                              void* d_out, int out_size, void* d_ws, size_t ws_size,
                              hipStream_t stream) {
  const float* x  = (const float*)d_in[0];
  const float* Wi = (const float*)d_in[1];
  const float* bi = (const float*)d_in[2];
  const float* Wh = (const float*)d_in[3];
  const float* bh = (const float*)d_in[4];
  float* out = (float*)d_out;

  hipLaunchKernelGGL(xi_gemm, dim3(256, 8), dim3(256), 0, stream, x, Wi, bi, out);

  // ws: flags 64 x 64B (4 KB) | h hi[2][64][1024] ushort (256 KB)
  const size_t need = 4096 + (size_t)2 * 64 * 1024 * sizeof(unsigned short);
  if (ws_size >= need) {
    unsigned* flags = (unsigned*)d_ws;
    unsigned short* hs = (unsigned short*)((char*)d_ws + 4096);
    hipMemsetAsync(d_ws, 0, 4096, stream);  // reset flags (capture-safe, replayed)
    const float* Wh_ = Wh; const float* bh_ = bh; float* out_ = out;
    void* args[] = {(void*)&Wh_, (void*)&bh_, (void*)&out_, (void*)&flags, (void*)&hs};

    const int lds16 = 64 * 1032 * 2;  // 132096 B dynamic LDS
    hipError_t e = hipFuncSetAttribute(
        reinterpret_cast<const void*>(rnn_persist16),
        hipFuncAttributeMaxDynamicSharedMemorySize, lds16);
    if (e == hipSuccess)
      e = hipLaunchCooperativeKernel((void*)rnn_persist16, dim3(NB16), dim3(1024),
                                     args, lds16, stream);
    if (e != hipSuccess) {
      // round-8 validated config
      hipLaunchCooperativeKernel((void*)rnn_persist64, dim3(NB64), dim3(256),
                                 args, 0, stream);
    }
  } else {
    // deterministic fallback (validated round 2)
    for (int t = 0; t < T_; ++t)
      hipLaunchKernelGGL(rnn_step, dim3(256), dim3(256), 0, stream, Wh, bh, out, t);
  }
}

// Round 10
// 3683.050 us; speedup vs baseline: 2.3669x; 2.3669x over previous
//
#include <hip/hip_runtime.h>
#include <hip/hip_bf16.h>

#define B_ 64
#define T_ 512
#define D_ 1024
#define H_ 1024

typedef __bf16 bf16x8 __attribute__((ext_vector_type(8)));
typedef float f32x4 __attribute__((ext_vector_type(4)));

static __device__ __forceinline__ unsigned short f2bf(float f) {
  union { float f; unsigned u; } v; v.f = f;
  unsigned u = v.u;
  unsigned r = (u + 0x7fffu + ((u >> 16) & 1u)) >> 16;
  return (unsigned short)r;
}

// ---------------------------------------------------------------------------
// xi = x @ Wi^T + bi -> out[B,T,H]  (validated rounds 2/5/6/7/8/9)
// ---------------------------------------------------------------------------
__global__ __launch_bounds__(256) void xi_gemm(const float* __restrict__ x,
                                               const float* __restrict__ Wi,
                                               const float* __restrict__ bi,
                                               float* __restrict__ out) {
  __shared__ __align__(16) unsigned short As[128][40];
  __shared__ __align__(16) unsigned short Ws[128][40];
  const int tid = threadIdx.x;
  const int wave = tid >> 6;
  const int lane = tid & 63;
  const int wm = wave >> 1, wn = wave & 1;
  const int lr = lane & 15, lk = lane >> 4;
  const long row0 = (long)blockIdx.x * 128;
  const int col0 = (int)blockIdx.y * 128;

  f32x4 acc[4][4];
#pragma unroll
  for (int m = 0; m < 4; ++m)
#pragma unroll
    for (int n = 0; n < 4; ++n)
      acc[m][n] = (f32x4){0.f, 0.f, 0.f, 0.f};

  for (int kt = 0; kt < 32; ++kt) {
    __syncthreads();
#pragma unroll
    for (int it = 0; it < 4; ++it) {
      int i = tid + it * 256;
      int row = i >> 3, c = i & 7;
      float4 va = *reinterpret_cast<const float4*>(
          &x[(row0 + row) * 1024 + kt * 32 + c * 4]);
      ushort4 ba = {f2bf(va.x), f2bf(va.y), f2bf(va.z), f2bf(va.w)};
      *reinterpret_cast<ushort4*>(&As[row][c * 4]) = ba;
      float4 vw = *reinterpret_cast<const float4*>(
          &Wi[(long)(col0 + row) * 1024 + kt * 32 + c * 4]);
      ushort4 bw = {f2bf(vw.x), f2bf(vw.y), f2bf(vw.z), f2bf(vw.w)};
      *reinterpret_cast<ushort4*>(&Ws[row][c * 4]) = bw;
    }
    __syncthreads();
    bf16x8 af[4], wf[4];
#pragma unroll
    for (int m = 0; m < 4; ++m)
      af[m] = *reinterpret_cast<const bf16x8*>(&As[wm * 64 + m * 16 + lr][lk * 8]);
#pragma unroll
    for (int n = 0; n < 4; ++n)
      wf[n] = *reinterpret_cast<const bf16x8*>(&Ws[wn * 64 + n * 16 + lr][lk * 8]);
#pragma unroll
    for (int m = 0; m < 4; ++m)
#pragma unroll
      for (int n = 0; n < 4; ++n)
        acc[m][n] = __builtin_amdgcn_mfma_f32_16x16x32_bf16(af[m], wf[n], acc[m][n], 0, 0, 0);
  }
#pragma unroll
  for (int m = 0; m < 4; ++m) {
#pragma unroll
    for (int n = 0; n < 4; ++n) {
#pragma unroll
      for (int r = 0; r < 4; ++r) {
        long row = row0 + wm * 64 + m * 16 + lk * 4 + r;
        int col = col0 + wn * 64 + n * 16 + lr;
        out[row * 1024 + col] = acc[m][n][r] + bi[col];
      }
    }
  }
}

// ---------------------------------------------------------------------------
// Persistent recurrence v5: XCD-LOCAL sync domains.
// 256 blocks x 64 thr (1 wave), dynamic LDS 66 KB.
// Phase 0: block reads physical XCC_ID (s_getreg, m09), registers via
// device-scope atomics, all blocks rendezvous, validate 32 blocks/XCD.
//  OK  -> FAST: XCD x owns batches 8x..8x+7; slot s owns j-cols 32s..32s+31.
//         Wh slice (32x1024 bf16, 64 KB) LDS-resident. h state (16 rows incl.
//         8 zero-pad x 1024 bf16, per parity) lives in the XCD's OWN L2:
//         plain stores + s_waitcnt vmcnt(0) publish (L1 write-through -> L2);
//         plain loads after acquire-inv consume (dirty L2 lines survive inv).
//         Only the per-step flags (32/XCD) cross to the LLC (agent atomics).
//  BAD -> FALLBACK: round-8 semantics, 256 blocks = 4 batch-groups x 64
//         j-groups, agent-atomic h publication + 256-flag LLC barrier.
// All spins capped (fail loud, never wedge).
// ws: ctrs 256B @0 | flagsF 16KB @4096 | flagsB 16KB @20480 |
//     hsF 512KB @36864 ([xcd][2][16][1024] ushort) | hsB 256KB @561152.
// ---------------------------------------------------------------------------
__global__ __launch_bounds__(64) void rnn_xcd(const float* __restrict__ Wh,
                                              const float* __restrict__ bh,
                                              float* __restrict__ out,
                                              unsigned* __restrict__ ctrs,
                                              unsigned* __restrict__ flagsF,
                                              unsigned* __restrict__ flagsB,
                                              unsigned short* __restrict__ hsF,
                                              unsigned short* __restrict__ hsB) {
  extern __shared__ __align__(16) unsigned short Whs[];
  const int lane = threadIdx.x;
  const int lr = lane & 15, lk = lane >> 4;

  // ---- phase 0: registration & placement validation (once per launch) ----
  unsigned xcc = 0, slot = 0, okv = 0;
  if (lane == 0) {
    xcc = __builtin_amdgcn_s_getreg((31u << 11) | 20u) & 15u;  // HW_REG_XCC_ID
    slot = __hip_atomic_fetch_add(&ctrs[xcc], 1u, __ATOMIC_RELAXED,
                                  __HIP_MEMORY_SCOPE_AGENT);
    __hip_atomic_fetch_add(&ctrs[16], 1u, __ATOMIC_RELEASE,
                           __HIP_MEMORY_SCOPE_AGENT);
    unsigned spin = 0;
    while (__hip_atomic_load(&ctrs[16], __ATOMIC_ACQUIRE,
                             __HIP_MEMORY_SCOPE_AGENT) < 256u) {
      __builtin_amdgcn_s_sleep(1);
      if (++spin > 2000000u) break;
    }
    unsigned ok = 1;
    for (int i = 0; i < 8; ++i)
      if (__hip_atomic_load(&ctrs[i], __ATOMIC_RELAXED,
                            __HIP_MEMORY_SCOPE_AGENT) != 32u) ok = 0;
    for (int i = 8; i < 16; ++i)
      if (__hip_atomic_load(&ctrs[i], __ATOMIC_RELAXED,
                            __HIP_MEMORY_SCOPE_AGENT) != 0u) ok = 0;
    okv = ok;
  }
  xcc  = (unsigned)__shfl((int)xcc, 0, 64);
  slot = (unsigned)__shfl((int)slot, 0, 64);
  okv  = (unsigned)__shfl((int)okv, 0, 64);

  if (okv) {
    // ==================== FAST PATH (XCD-local) ====================
    const int j0 = (int)slot * 32;
    // stage Wh rows j0..j0+31 -> LDS [32][1032] bf16 (once)
#pragma unroll 8
    for (int it = 0; it < 128; ++it) {
      int i = lane + it * 64;
      int row = i >> 8, c = i & 255;
      float4 v = *reinterpret_cast<const float4*>(&Wh[(long)(j0 + row) * 1024 + c * 4]);
      ushort4 b4 = {f2bf(v.x), f2bf(v.y), f2bf(v.z), f2bf(v.w)};
      *reinterpret_cast<ushort4*>(&Whs[row * 1032 + c * 4]) = b4;
    }
    __syncthreads();  // LDS writes visible wave-wide (lgkm drain)

    const int jc0 = j0 + lr;         // tile-0 col
    const int jc1 = j0 + 16 + lr;    // tile-1 col
    const float bhv0 = bh[jc0], bhv1 = bh[jc1];
    const unsigned short* wb0 = &Whs[lr * 1032 + lk * 8];
    const unsigned short* wb1 = &Whs[(16 + lr) * 1032 + lk * 8];
    unsigned* hw = reinterpret_cast<unsigned*>(hsF);
    const unsigned fslot = (xcc * 32u + slot) << 4;

    for (int t = 0; t < T_; ++t) {
      // xi prefetch (rows valid for lk<2) — hides LLC latency under barrier
      float xr0[4], xr1[4];
      if (lk < 2) {
#pragma unroll
        for (int r = 0; r < 4; ++r) {
          size_t oi = ((size_t)(xcc * 8 + lk * 4 + r) * T_ + t) * H_;
          xr0[r] = out[oi + jc0];
          xr1[r] = out[oi + jc1];
        }
      }
      if (t > 0) {
        asm volatile("s_waitcnt vmcnt(0)" ::: "memory");  // h stores in L2
        if (lane == 0)
          __hip_atomic_store(&flagsF[fslot], (unsigned)t,
                             __ATOMIC_RELAXED, __HIP_MEMORY_SCOPE_AGENT);
        unsigned spin = 0;
        for (;;) {
          unsigned v = (unsigned)t;
          if (lane < 32)
            v = __hip_atomic_load(&flagsF[(xcc * 32u + (unsigned)lane) << 4],
                                  __ATOMIC_RELAXED, __HIP_MEMORY_SCOPE_AGENT);
          if (__all((int)(v >= (unsigned)t))) break;
          __builtin_amdgcn_s_sleep(1);
          if (++spin > 50000u) break;  // fail loud, never wedge
        }
        __builtin_amdgcn_fence(__ATOMIC_ACQUIRE, "agent");  // inv L1/L2-clean
      }

      f32x4 a00 = {0,0,0,0}, a01 = {0,0,0,0}, a10 = {0,0,0,0}, a11 = {0,0,0,0};
      if (t > 0) {
        const unsigned short* hp = hsF + (size_t)xcc * 32768 +
                                   (size_t)((t - 1) & 1) * 16384 +
                                   (size_t)lr * 1024 + lk * 8;
#pragma unroll 4
        for (int ks = 0; ks < 16; ++ks) {
          bf16x8 ah0 = *reinterpret_cast<const bf16x8*>(hp + ks * 32);
          bf16x8 ah1 = *reinterpret_cast<const bf16x8*>(hp + (ks + 16) * 32);
          bf16x8 w00 = *reinterpret_cast<const bf16x8*>(wb0 + ks * 32);
          bf16x8 w01 = *reinterpret_cast<const bf16x8*>(wb0 + (ks + 16) * 32);
          bf16x8 w10 = *reinterpret_cast<const bf16x8*>(wb1 + ks * 32);
          bf16x8 w11 = *reinterpret_cast<const bf16x8*>(wb1 + (ks + 16) * 32);
          a00 = __builtin_amdgcn_mfma_f32_16x16x32_bf16(ah0, w00, a00, 0, 0, 0);
          a01 = __builtin_amdgcn_mfma_f32_16x16x32_bf16(ah1, w01, a01, 0, 0, 0);
          a10 = __builtin_amdgcn_mfma_f32_16x16x32_bf16(ah0, w10, a10, 0, 0, 0);
          a11 = __builtin_amdgcn_mfma_f32_16x16x32_bf16(ah1, w11, a11, 0, 0, 0);
        }
      }
      f32x4 acc0 = a00 + a01, acc1 = a10 + a11;

      // epilogue: D rows lk*4+r; real batches = rows 0..7 (lk<2); rows 8..15
      // of hsF are zero-pad (memset at launch), never written, never stored.
      const unsigned pw = (unsigned)(t & 1) * 8192u;
      if (lk < 2) {
#pragma unroll
        for (int r = 0; r < 4; ++r) {
          int row = lk * 4 + r;                  // 0..7
          size_t oi = ((size_t)(xcc * 8 + row) * T_ + t) * H_;
          float h0 = tanhf(xr0[r] + acc0[r] + bhv0);
          float h1 = tanhf(xr1[r] + acc1[r] + bhv1);
          out[oi + jc0] = h0;
          out[oi + jc1] = h1;
          unsigned u0 = f2bf(h0), u1 = f2bf(h1);
          unsigned o0 = (unsigned)__shfl_xor((int)u0, 1, 64);
          unsigned o1 = (unsigned)__shfl_xor((int)u1, 1, 64);
          if ((lr & 1) == 0) {  // plain cached stores -> own XCD's L2
            unsigned base = xcc * 16384u + pw + (unsigned)row * 512u;
            hw[base + ((unsigned)jc0 >> 1)] = u0 | (o0 << 16);
            hw[base + ((unsigned)jc1 >> 1)] = u1 | (o1 << 16);
          }
        }
      }
    }
  } else {
    // ==================== FALLBACK (LLC-synced, round-8 semantics) =========
    const int bid = (int)blockIdx.x;         // 256 blocks: 4 bgroups x 64 jgroups
    const int jg = bid & 63, bg = bid >> 6;
    const int j0 = jg * 16, brow = bg * 16;
#pragma unroll 8
    for (int it = 0; it < 64; ++it) {
      int i = lane + it * 64;
      int row = i >> 8, c = i & 255;
      float4 v = *reinterpret_cast<const float4*>(&Wh[(long)(j0 + row) * 1024 + c * 4]);
      ushort4 b4 = {f2bf(v.x), f2bf(v.y), f2bf(v.z), f2bf(v.w)};
      *reinterpret_cast<ushort4*>(&Whs[row * 1032 + c * 4]) = b4;
    }
    __syncthreads();
    const int jcol = j0 + lr;
    const float bhv = bh[jcol];
    const unsigned short* wbl = &Whs[lr * 1032 + lk * 8];
    unsigned* hw = reinterpret_cast<unsigned*>(hsB);
    const int jp = jcol >> 1;

    for (int t = 0; t < T_; ++t) {
      if (t > 0) {
        asm volatile("s_waitcnt vmcnt(0)" ::: "memory");
        if (lane == 0)
          __hip_atomic_store(&flagsB[(unsigned)bid << 4], (unsigned)t,
                             __ATOMIC_RELAXED, __HIP_MEMORY_SCOPE_AGENT);
        unsigned spin = 0;
        for (;;) {
          unsigned va = (unsigned)t, vb = va, vc = va, vd = va;
          va = __hip_atomic_load(&flagsB[(unsigned)lane << 4],
                                 __ATOMIC_RELAXED, __HIP_MEMORY_SCOPE_AGENT);
          vb = __hip_atomic_load(&flagsB[((unsigned)lane + 64u) << 4],
                                 __ATOMIC_RELAXED, __HIP_MEMORY_SCOPE_AGENT);
          vc = __hip_atomic_load(&flagsB[((unsigned)lane + 128u) << 4],
                                 __ATOMIC_RELAXED, __HIP_MEMORY_SCOPE_AGENT);
          vd = __hip_atomic_load(&flagsB[((unsigned)lane + 192u) << 4],
                                 __ATOMIC_RELAXED, __HIP_MEMORY_SCOPE_AGENT);
          int ok = (va >= (unsigned)t) && (vb >= (unsigned)t) &&
                   (vc >= (unsigned)t) && (vd >= (unsigned)t);
          if (__all(ok)) break;
          __builtin_amdgcn_s_sleep(2);
          if (++spin > 50000u) break;
        }
        __builtin_amdgcn_fence(__ATOMIC_ACQUIRE, "agent");
      }

      f32x4 a0 = {0,0,0,0}, a1 = {0,0,0,0};
      if (t > 0) {
        const unsigned short* hbl = hsB + (size_t)((t - 1) & 1) * 65536 +
                                    (size_t)(brow + lr) * 1024 + lk * 8;
#pragma unroll 4
        for (int ks = 0; ks < 16; ++ks) {
          bf16x8 ah0 = *reinterpret_cast<const bf16x8*>(hbl + ks * 32);
          bf16x8 ah1 = *reinterpret_cast<const bf16x8*>(hbl + (ks + 16) * 32);
          bf16x8 wf0 = *reinterpret_cast<const bf16x8*>(wbl + ks * 32);
          bf16x8 wf1 = *reinterpret_cast<const bf16x8*>(wbl + (ks + 16) * 32);
          a0 = __builtin_amdgcn_mfma_f32_16x16x32_bf16(ah0, wf0, a0, 0, 0, 0);
          a1 = __builtin_amdgcn_mfma_f32_16x16x32_bf16(ah1, wf1, a1, 0, 0, 0);
        }
      }
      f32x4 acc = a0 + a1;

      const unsigned pw = (unsigned)(t & 1) * 32768u;
#pragma unroll
      for (int r = 0; r < 4; ++r) {
        int b = brow + lk * 4 + r;
        size_t oi = ((size_t)b * T_ + t) * H_ + jcol;
        float z = out[oi] + acc[r] + bhv;
        float h = tanhf(z);
        out[oi] = h;
        unsigned hi_u = f2bf(h);
        unsigned o_hi = (unsigned)__shfl_xor((int)hi_u, 1, 64);
        if ((lr & 1) == 0) {
          __hip_atomic_store(&hw[pw + (unsigned)b * 512u + (unsigned)jp],
                             hi_u | (o_hi << 16),
                             __ATOMIC_RELAXED, __HIP_MEMORY_SCOPE_AGENT);
        }
      }
    }
  }
}

// ---------------------------------------------------------------------------
// Last-resort fallback (round-2 validated): per-step kernel chain.
// ---------------------------------------------------------------------------
__global__ __launch_bounds__(256) void rnn_step(const float* __restrict__ Wh,
                                                const float* __restrict__ bh,
                                                float* __restrict__ out,
                                                int t) {
  const int bg = blockIdx.x & 3;
  const int jg = blockIdx.x >> 2;
  const int b = bg * 16 + (threadIdx.x >> 4);
  const int j = jg * 16 + (threadIdx.x & 15);
  float a0 = 0.f, a1 = 0.f, a2 = 0.f, a3 = 0.f;
  if (t > 0) {
    const float4* __restrict__ wr = reinterpret_cast<const float4*>(&Wh[(long)j * H_]);
    const float4* __restrict__ hr = reinterpret_cast<const float4*>(
        &out[((long)b * T_ + (t - 1)) * H_]);
#pragma unroll 8
    for (int kc = 0; kc < 256; ++kc) {
      float4 w = wr[kc];
      float4 h = hr[kc];
      a0 = fmaf(w.x, h.x, a0);
      a1 = fmaf(w.y, h.y, a1);
      a2 = fmaf(w.z, h.z, a2);
      a3 = fmaf(w.w, h.w, a3);
    }
  }
  const long oi = ((long)b * T_ + t) * H_ + j;
  float z = out[oi] + ((a0 + a1) + (a2 + a3)) + bh[j];
  out[oi] = tanhf(z);
}

extern "C" void kernel_launch(void* const* d_in, const int* in_sizes, int n_in,
                              void* d_out, int out_size, void* d_ws, size_t ws_size,
                              hipStream_t stream) {
  const float* x  = (const float*)d_in[0];
  const float* Wi = (const float*)d_in[1];
  const float* bi = (const float*)d_in[2];
  const float* Wh = (const float*)d_in[3];
  const float* bh = (const float*)d_in[4];
  float* out = (float*)d_out;

  // ws layout
  const size_t CTRS_OFF  = 0;        // 256 B
  const size_t FLAGF_OFF = 4096;     // 16 KB
  const size_t FLAGB_OFF = 20480;    // 16 KB
  const size_t HSF_OFF   = 36864;    // 512 KB ([8][2][16][1024] ushort)
  const size_t HSB_OFF   = 561152;   // 256 KB ([2][64][1024] ushort)
  const size_t NEED      = HSB_OFF + 262144;

  hipLaunchKernelGGL(xi_gemm, dim3(256, 8), dim3(256), 0, stream, x, Wi, bi, out);

  bool launched = false;
  if (ws_size >= NEED) {
    unsigned* ctrs = (unsigned*)((char*)d_ws + CTRS_OFF);
    unsigned* flagsF = (unsigned*)((char*)d_ws + FLAGF_OFF);
    unsigned* flagsB = (unsigned*)((char*)d_ws + FLAGB_OFF);
    unsigned short* hsF = (unsigned short*)((char*)d_ws + HSF_OFF);
    unsigned short* hsB = (unsigned short*)((char*)d_ws + HSB_OFF);
    // zero ctrs + both flag arrays + hsF (pad rows must be 0 every call)
    hipMemsetAsync(d_ws, 0, HSF_OFF + 524288, stream);

    const float* Wh_ = Wh; const float* bh_ = bh; float* out_ = out;
    void* args[] = {(void*)&Wh_, (void*)&bh_, (void*)&out_,
                    (void*)&ctrs, (void*)&flagsF, (void*)&flagsB,
                    (void*)&hsF, (void*)&hsB};
    const int lds = 32 * 1032 * 2;  // 66048 B dynamic LDS
    hipError_t e = hipFuncSetAttribute(
        reinterpret_cast<const void*>(rnn_xcd),
        hipFuncAttributeMaxDynamicSharedMemorySize, lds);
    if (e == hipSuccess)
      e = hipLaunchCooperativeKernel((void*)rnn_xcd, dim3(256), dim3(64),
                                     args, lds, stream);
    launched = (e == hipSuccess);
  }
  if (!launched) {
    // deterministic last resort (validated round 2)
    for (int t = 0; t < T_; ++t)
      hipLaunchKernelGGL(rnn_step, dim3(256), dim3(256), 0, stream, Wh, bh, out, t);
  }
}

// Round 12
// 3380.999 us; speedup vs baseline: 2.5783x; 1.0893x over previous
//
#include <hip/hip_runtime.h>
#include <hip/hip_bf16.h>

#define B_ 64
#define T_ 512
#define D_ 1024
#define H_ 1024

typedef __bf16 bf16x8 __attribute__((ext_vector_type(8)));
typedef float f32x4 __attribute__((ext_vector_type(4)));

static __device__ __forceinline__ unsigned short f2bf(float f) {
  union { float f; unsigned u; } v; v.f = f;
  unsigned u = v.u;
  unsigned r = (u + 0x7fffu + ((u >> 16) & 1u)) >> 16;
  return (unsigned short)r;
}

// ---------------------------------------------------------------------------
// xi = x @ Wi^T + bi -> out[B,T,H]  (validated rounds 2/5/6/7/8/9/10)
// ---------------------------------------------------------------------------
__global__ __launch_bounds__(256) void xi_gemm(const float* __restrict__ x,
                                               const float* __restrict__ Wi,
                                               const float* __restrict__ bi,
                                               float* __restrict__ out) {
  __shared__ __align__(16) unsigned short As[128][40];
  __shared__ __align__(16) unsigned short Ws[128][40];
  const int tid = threadIdx.x;
  const int wave = tid >> 6;
  const int lane = tid & 63;
  const int wm = wave >> 1, wn = wave & 1;
  const int lr = lane & 15, lk = lane >> 4;
  const long row0 = (long)blockIdx.x * 128;
  const int col0 = (int)blockIdx.y * 128;

  f32x4 acc[4][4];
#pragma unroll
  for (int m = 0; m < 4; ++m)
#pragma unroll
    for (int n = 0; n < 4; ++n)
      acc[m][n] = (f32x4){0.f, 0.f, 0.f, 0.f};

  for (int kt = 0; kt < 32; ++kt) {
    __syncthreads();
#pragma unroll
    for (int it = 0; it < 4; ++it) {
      int i = tid + it * 256;
      int row = i >> 3, c = i & 7;
      float4 va = *reinterpret_cast<const float4*>(
          &x[(row0 + row) * 1024 + kt * 32 + c * 4]);
      ushort4 ba = {f2bf(va.x), f2bf(va.y), f2bf(va.z), f2bf(va.w)};
      *reinterpret_cast<ushort4*>(&As[row][c * 4]) = ba;
      float4 vw = *reinterpret_cast<const float4*>(
          &Wi[(long)(col0 + row) * 1024 + kt * 32 + c * 4]);
      ushort4 bw = {f2bf(vw.x), f2bf(vw.y), f2bf(vw.z), f2bf(vw.w)};
      *reinterpret_cast<ushort4*>(&Ws[row][c * 4]) = bw;
    }
    __syncthreads();
    bf16x8 af[4], wf[4];
#pragma unroll
    for (int m = 0; m < 4; ++m)
      af[m] = *reinterpret_cast<const bf16x8*>(&As[wm * 64 + m * 16 + lr][lk * 8]);
#pragma unroll
    for (int n = 0; n < 4; ++n)
      wf[n] = *reinterpret_cast<const bf16x8*>(&Ws[wn * 64 + n * 16 + lr][lk * 8]);
#pragma unroll
    for (int m = 0; m < 4; ++m)
#pragma unroll
      for (int n = 0; n < 4; ++n)
        acc[m][n] = __builtin_amdgcn_mfma_f32_16x16x32_bf16(af[m], wf[n], acc[m][n], 0, 0, 0);
  }
#pragma unroll
  for (int m = 0; m < 4; ++m) {
#pragma unroll
    for (int n = 0; n < 4; ++n) {
#pragma unroll
      for (int r = 0; r < 4; ++r) {
        long row = row0 + wm * 64 + m * 16 + lk * 4 + r;
        int col = col0 + wn * 64 + n * 16 + lr;
        out[row * 1024 + col] = acc[m][n][r] + bi[col];
      }
    }
  }
}

// ---------------------------------------------------------------------------
// Persistent recurrence v7 = round-10 protocol (replay-proven) + xi prefetch
// moved off the drain path.
// 256 blocks x 64 thr, dynamic LDS 66 KB. Registration phase: s_getreg
// XCC_ID + device-atomic rendezvous (validated r10).
// FAST step protocol:
//   s_waitcnt vmcnt(0)            h+out stores retired (L2-fast; xi NOT here)
//   flag: agent atomic store t    -> LLC (replay-safe: memset resets at LLC,
//                                  polls are agent atomics reading LLC)
//   xi prefetch issue             HBM latency hides under the LLC poll
//   poll: agent atomic loads of own XCD's 32 flags until all >= t
//   fence(acquire,"agent")        inv L1/L2-clean; dirty h lines survive;
//                                 xi already drained into regs by the poll
//   h cached loads + MFMA (Wh from LDS) -> tanh -> plain stores (h -> L2)
// BAD placement -> FALLBACK: round-8-semantics LLC path (validated).
// ws: ctrs 256B @0 | flagsF 16KB @4096 | flagsB 16KB @20480 |
//     hsF 512KB @36864 ([xcd][2][16][1024] ushort) | hsB 256KB @561152.
// ---------------------------------------------------------------------------
__global__ __launch_bounds__(64) void rnn_xcd(const float* __restrict__ Wh,
                                              const float* __restrict__ bh,
                                              float* __restrict__ out,
                                              unsigned* __restrict__ ctrs,
                                              unsigned* __restrict__ flagsF,
                                              unsigned* __restrict__ flagsB,
                                              unsigned short* __restrict__ hsF,
                                              unsigned short* __restrict__ hsB) {
  extern __shared__ __align__(16) unsigned short Whs[];
  const int lane = threadIdx.x;
  const int lr = lane & 15, lk = lane >> 4;

  // ---- phase 0: registration & placement validation (round-10 validated) ----
  unsigned xcc = 0, slot = 0, okv = 0;
  if (lane == 0) {
    xcc = __builtin_amdgcn_s_getreg((31u << 11) | 20u) & 15u;  // HW_REG_XCC_ID
    slot = __hip_atomic_fetch_add(&ctrs[xcc], 1u, __ATOMIC_RELAXED,
                                  __HIP_MEMORY_SCOPE_AGENT);
    __hip_atomic_fetch_add(&ctrs[16], 1u, __ATOMIC_RELEASE,
                           __HIP_MEMORY_SCOPE_AGENT);
    unsigned spin = 0;
    while (__hip_atomic_load(&ctrs[16], __ATOMIC_ACQUIRE,
                             __HIP_MEMORY_SCOPE_AGENT) < 256u) {
      __builtin_amdgcn_s_sleep(1);
      if (++spin > 2000000u) break;
    }
    unsigned ok = 1;
    for (int i = 0; i < 8; ++i)
      if (__hip_atomic_load(&ctrs[i], __ATOMIC_RELAXED,
                            __HIP_MEMORY_SCOPE_AGENT) != 32u) ok = 0;
    for (int i = 8; i < 16; ++i)
      if (__hip_atomic_load(&ctrs[i], __ATOMIC_RELAXED,
                            __HIP_MEMORY_SCOPE_AGENT) != 0u) ok = 0;
    okv = ok;
  }
  xcc  = (unsigned)__shfl((int)xcc, 0, 64);
  slot = (unsigned)__shfl((int)slot, 0, 64);
  okv  = (unsigned)__shfl((int)okv, 0, 64);

  if (okv) {
    // ==================== FAST PATH (XCD-local data, LLC flags) ============
    const int j0 = (int)slot * 32;
#pragma unroll 8
    for (int it = 0; it < 128; ++it) {
      int i = lane + it * 64;
      int row = i >> 8, c = i & 255;
      float4 v = *reinterpret_cast<const float4*>(&Wh[(long)(j0 + row) * 1024 + c * 4]);
      ushort4 b4 = {f2bf(v.x), f2bf(v.y), f2bf(v.z), f2bf(v.w)};
      *reinterpret_cast<ushort4*>(&Whs[row * 1032 + c * 4]) = b4;
    }
    __syncthreads();

    const int jc0 = j0 + lr;
    const int jc1 = j0 + 16 + lr;
    const float bhv0 = bh[jc0], bhv1 = bh[jc1];
    const unsigned short* wb0 = &Whs[lr * 1032 + lk * 8];
    const unsigned short* wb1 = &Whs[(16 + lr) * 1032 + lk * 8];
    unsigned* hw = reinterpret_cast<unsigned*>(hsF);
    const unsigned fslot = (xcc * 32u + slot) << 4;

    for (int t = 0; t < T_; ++t) {
      float xr0[4], xr1[4];
      if (t > 0) {
        // drain = h+out stores only (xi deliberately NOT outstanding here)
        asm volatile("s_waitcnt vmcnt(0)" ::: "memory");
        if (lane == 0)
          __hip_atomic_store(&flagsF[fslot], (unsigned)t,
                             __ATOMIC_RELAXED, __HIP_MEMORY_SCOPE_AGENT);
        // xi prefetch issued now — HBM latency hides under the LLC poll;
        // each poll iteration's atomic load drains vmcnt -> xi lands in regs
        // before the fence (registers unaffected by cache-inv).
        if (lk < 2) {
#pragma unroll
          for (int r = 0; r < 4; ++r) {
            size_t oi = ((size_t)(xcc * 8 + lk * 4 + r) * T_ + t) * H_;
            xr0[r] = out[oi + jc0];
            xr1[r] = out[oi + jc1];
          }
        }
        unsigned spin = 0;
        for (;;) {
          unsigned v = (unsigned)t;
          if (lane < 32)
            v = __hip_atomic_load(&flagsF[(xcc * 32u + (unsigned)lane) << 4],
                                  __ATOMIC_RELAXED, __HIP_MEMORY_SCOPE_AGENT);
          if (__all((int)(v >= (unsigned)t))) break;
          if (spin >= 2) __builtin_amdgcn_s_sleep(1);
          if (++spin > 50000u) break;  // fail loud, never wedge
        }
        __builtin_amdgcn_fence(__ATOMIC_ACQUIRE, "agent");  // inv L1/L2-clean
      } else {
        if (lk < 2) {
#pragma unroll
          for (int r = 0; r < 4; ++r) {
            size_t oi = ((size_t)(xcc * 8 + lk * 4 + r) * T_ + t) * H_;
            xr0[r] = out[oi + jc0];
            xr1[r] = out[oi + jc1];
          }
        }
      }

      f32x4 a00 = {0,0,0,0}, a01 = {0,0,0,0}, a10 = {0,0,0,0}, a11 = {0,0,0,0};
      if (t > 0) {
        const unsigned short* hp = hsF + (size_t)xcc * 32768 +
                                   (size_t)((t - 1) & 1) * 16384 +
                                   (size_t)lr * 1024 + lk * 8;
#pragma unroll 4
        for (int ks = 0; ks < 16; ++ks) {
          bf16x8 ah0 = *reinterpret_cast<const bf16x8*>(hp + ks * 32);
          bf16x8 ah1 = *reinterpret_cast<const bf16x8*>(hp + (ks + 16) * 32);
          bf16x8 w00 = *reinterpret_cast<const bf16x8*>(wb0 + ks * 32);
          bf16x8 w01 = *reinterpret_cast<const bf16x8*>(wb0 + (ks + 16) * 32);
          bf16x8 w10 = *reinterpret_cast<const bf16x8*>(wb1 + ks * 32);
          bf16x8 w11 = *reinterpret_cast<const bf16x8*>(wb1 + (ks + 16) * 32);
          a00 = __builtin_amdgcn_mfma_f32_16x16x32_bf16(ah0, w00, a00, 0, 0, 0);
          a01 = __builtin_amdgcn_mfma_f32_16x16x32_bf16(ah1, w01, a01, 0, 0, 0);
          a10 = __builtin_amdgcn_mfma_f32_16x16x32_bf16(ah0, w10, a10, 0, 0, 0);
          a11 = __builtin_amdgcn_mfma_f32_16x16x32_bf16(ah1, w11, a11, 0, 0, 0);
        }
      }
      f32x4 acc0 = a00 + a01, acc1 = a10 + a11;

      // epilogue: D rows lk*4+r; real batches = rows 0..7 (lk<2); rows 8..15
      // of hsF are zero-pad (memset at launch), never written.
      const unsigned pw = (unsigned)(t & 1) * 8192u;
      if (lk < 2) {
#pragma unroll
        for (int r = 0; r < 4; ++r) {
          int row = lk * 4 + r;                  // 0..7
          size_t oi = ((size_t)(xcc * 8 + row) * T_ + t) * H_;
          float h0 = tanhf(xr0[r] + acc0[r] + bhv0);
          float h1 = tanhf(xr1[r] + acc1[r] + bhv1);
          out[oi + jc0] = h0;
          out[oi + jc1] = h1;
          unsigned u0 = f2bf(h0), u1 = f2bf(h1);
          unsigned o0 = (unsigned)__shfl_xor((int)u0, 1, 64);
          unsigned o1 = (unsigned)__shfl_xor((int)u1, 1, 64);
          if ((lr & 1) == 0) {  // plain cached stores -> own XCD's L2
            unsigned base = xcc * 16384u + pw + (unsigned)row * 512u;
            hw[base + ((unsigned)jc0 >> 1)] = u0 | (o0 << 16);
            hw[base + ((unsigned)jc1 >> 1)] = u1 | (o1 << 16);
          }
        }
      }
    }
  } else {
    // ============== FALLBACK (LLC-synced, round-8 semantics, validated) ====
    const int bid = (int)blockIdx.x;
    const int jg = bid & 63, bg = bid >> 6;
    const int j0 = jg * 16, brow = bg * 16;
#pragma unroll 8
    for (int it = 0; it < 64; ++it) {
      int i = lane + it * 64;
      int row = i >> 8, c = i & 255;
      float4 v = *reinterpret_cast<const float4*>(&Wh[(long)(j0 + row) * 1024 + c * 4]);
      ushort4 b4 = {f2bf(v.x), f2bf(v.y), f2bf(v.z), f2bf(v.w)};
      *reinterpret_cast<ushort4*>(&Whs[row * 1032 + c * 4]) = b4;
    }
    __syncthreads();
    const int jcol = j0 + lr;
    const float bhv = bh[jcol];
    const unsigned short* wbl = &Whs[lr * 1032 + lk * 8];
    unsigned* hw = reinterpret_cast<unsigned*>(hsB);
    const int jp = jcol >> 1;

    for (int t = 0; t < T_; ++t) {
      if (t > 0) {
        asm volatile("s_waitcnt vmcnt(0)" ::: "memory");
        if (lane == 0)
          __hip_atomic_store(&flagsB[(unsigned)bid << 4], (unsigned)t,
                             __ATOMIC_RELAXED, __HIP_MEMORY_SCOPE_AGENT);
        unsigned spin = 0;
        for (;;) {
          unsigned va = __hip_atomic_load(&flagsB[(unsigned)lane << 4],
                                 __ATOMIC_RELAXED, __HIP_MEMORY_SCOPE_AGENT);
          unsigned vb = __hip_atomic_load(&flagsB[((unsigned)lane + 64u) << 4],
                                 __ATOMIC_RELAXED, __HIP_MEMORY_SCOPE_AGENT);
          unsigned vc = __hip_atomic_load(&flagsB[((unsigned)lane + 128u) << 4],
                                 __ATOMIC_RELAXED, __HIP_MEMORY_SCOPE_AGENT);
          unsigned vd = __hip_atomic_load(&flagsB[((unsigned)lane + 192u) << 4],
                                 __ATOMIC_RELAXED, __HIP_MEMORY_SCOPE_AGENT);
          int ok = (va >= (unsigned)t) && (vb >= (unsigned)t) &&
                   (vc >= (unsigned)t) && (vd >= (unsigned)t);
          if (__all(ok)) break;
          __builtin_amdgcn_s_sleep(2);
          if (++spin > 50000u) break;
        }
        __builtin_amdgcn_fence(__ATOMIC_ACQUIRE, "agent");
      }

      f32x4 a0 = {0,0,0,0}, a1 = {0,0,0,0};
      if (t > 0) {
        const unsigned short* hbl = hsB + (size_t)((t - 1) & 1) * 65536 +
                                    (size_t)(brow + lr) * 1024 + lk * 8;
#pragma unroll 4
        for (int ks = 0; ks < 16; ++ks) {
          bf16x8 ah0 = *reinterpret_cast<const bf16x8*>(hbl + ks * 32);
          bf16x8 ah1 = *reinterpret_cast<const bf16x8*>(hbl + (ks + 16) * 32);
          bf16x8 wf0 = *reinterpret_cast<const bf16x8*>(wbl + ks * 32);
          bf16x8 wf1 = *reinterpret_cast<const bf16x8*>(wbl + (ks + 16) * 32);
          a0 = __builtin_amdgcn_mfma_f32_16x16x32_bf16(ah0, wf0, a0, 0, 0, 0);
          a1 = __builtin_amdgcn_mfma_f32_16x16x32_bf16(ah1, wf1, a1, 0, 0, 0);
        }
      }
      f32x4 acc = a0 + a1;

      const unsigned pw = (unsigned)(t & 1) * 32768u;
#pragma unroll
      for (int r = 0; r < 4; ++r) {
        int b = brow + lk * 4 + r;
        size_t oi = ((size_t)b * T_ + t) * H_ + jcol;
        float z = out[oi] + acc[r] + bhv;
        float h = tanhf(z);
        out[oi] = h;
        unsigned hi_u = f2bf(h);
        unsigned o_hi = (unsigned)__shfl_xor((int)hi_u, 1, 64);
        if ((lr & 1) == 0) {
          __hip_atomic_store(&hw[pw + (unsigned)b * 512u + (unsigned)jp],
                             hi_u | (o_hi << 16),
                             __ATOMIC_RELAXED, __HIP_MEMORY_SCOPE_AGENT);
        }
      }
    }
  }
}

// ---------------------------------------------------------------------------
// Last-resort fallback (round-2 validated): per-step kernel chain.
// ---------------------------------------------------------------------------
__global__ __launch_bounds__(256) void rnn_step(const float* __restrict__ Wh,
                                                const float* __restrict__ bh,
                                                float* __restrict__ out,
                                                int t) {
  const int bg = blockIdx.x & 3;
  const int jg = blockIdx.x >> 2;
  const int b = bg * 16 + (threadIdx.x >> 4);
  const int j = jg * 16 + (threadIdx.x & 15);
  float a0 = 0.f, a1 = 0.f, a2 = 0.f, a3 = 0.f;
  if (t > 0) {
    const float4* __restrict__ wr = reinterpret_cast<const float4*>(&Wh[(long)j * H_]);
    const float4* __restrict__ hr = reinterpret_cast<const float4*>(
        &out[((long)b * T_ + (t - 1)) * H_]);
#pragma unroll 8
    for (int kc = 0; kc < 256; ++kc) {
      float4 w = wr[kc];
      float4 h = hr[kc];
      a0 = fmaf(w.x, h.x, a0);
      a1 = fmaf(w.y, h.y, a1);
      a2 = fmaf(w.z, h.z, a2);
      a3 = fmaf(w.w, h.w, a3);
    }
  }
  const long oi = ((long)b * T_ + t) * H_ + j;
  float z = out[oi] + ((a0 + a1) + (a2 + a3)) + bh[j];
  out[oi] = tanhf(z);
}

extern "C" void kernel_launch(void* const* d_in, const int* in_sizes, int n_in,
                              void* d_out, int out_size, void* d_ws, size_t ws_size,
                              hipStream_t stream) {
  const float* x  = (const float*)d_in[0];
  const float* Wi = (const float*)d_in[1];
  const float* bi = (const float*)d_in[2];
  const float* Wh = (const float*)d_in[3];
  const float* bh = (const float*)d_in[4];
  float* out = (float*)d_out;

  const size_t CTRS_OFF  = 0;        // 256 B
  const size_t FLAGF_OFF = 4096;     // 16 KB
  const size_t FLAGB_OFF = 20480;    // 16 KB
  const size_t HSF_OFF   = 36864;    // 512 KB ([8][2][16][1024] ushort)
  const size_t HSB_OFF   = 561152;   // 256 KB ([2][64][1024] ushort)
  const size_t NEED      = HSB_OFF + 262144;

  hipLaunchKernelGGL(xi_gemm, dim3(256, 8), dim3(256), 0, stream, x, Wi, bi, out);

  bool launched = false;
  if (ws_size >= NEED) {
    unsigned* ctrs = (unsigned*)((char*)d_ws + CTRS_OFF);
    unsigned* flagsF = (unsigned*)((char*)d_ws + FLAGF_OFF);
    unsigned* flagsB = (unsigned*)((char*)d_ws + FLAGB_OFF);
    unsigned short* hsF = (unsigned short*)((char*)d_ws + HSF_OFF);
    unsigned short* hsB = (unsigned short*)((char*)d_ws + HSB_OFF);
    // zero ctrs + both flag arrays + hsF (pad rows must be 0 every call)
    hipMemsetAsync(d_ws, 0, HSF_OFF + 524288, stream);

    const float* Wh_ = Wh; const float* bh_ = bh; float* out_ = out;
    void* args[] = {(void*)&Wh_, (void*)&bh_, (void*)&out_,
                    (void*)&ctrs, (void*)&flagsF, (void*)&flagsB,
                    (void*)&hsF, (void*)&hsB};
    const int lds = 32 * 1032 * 2;  // 66048 B dynamic LDS
    hipError_t e = hipFuncSetAttribute(
        reinterpret_cast<const void*>(rnn_xcd),
        hipFuncAttributeMaxDynamicSharedMemorySize, lds);
    if (e == hipSuccess)
      e = hipLaunchCooperativeKernel((void*)rnn_xcd, dim3(256), dim3(64),
                                     args, lds, stream);
    launched = (e == hipSuccess);
  }
  if (!launched) {
    for (int t = 0; t < T_; ++t)
      hipLaunchKernelGGL(rnn_step, dim3(256), dim3(256), 0, stream, Wh, bh, out, t);
  }
}